// Round 4
// baseline (135.676 us; speedup 1.0000x reference)
//
#include <hip/hip_runtime.h>
#include <cstdint>
#include <cstddef>

// ============================================================================
// ProposalTargetLayer (MSDN / Faster-RCNN), gfx950. Round 4.
// Pipeline: k_prep -> k_select -> k_final   (3 dispatches, no memset)
//  - k_prep: 4 rois/thread -> 4x fewer LDS reads of the gt tile and 4-way
//    ILP per ds_read (fixes the LDS-latency-bound 128-iter loop). fg mask
//    via exact divide-free f32 fma test; PRNG; vb value-bits. No argmax.
//  - k_select: histogram built in the load pass (LDS atomics), scan ->
//    threshold bin -> filtered L2 re-read pass -> exact rank (~K+6 cands).
//  - k_final: reference-exact argmax (f32 div, strict >, first-win) for the
//    4096 selected rois only; bbox transform + outputs. Grid (16,2)x128.
// Bit-exact discrete decisions (verified rounds 1-3, absmax 0.0):
//  * fg: round(inter/denom)>=0.5 <=> fmaf(-.5,den,inter) >= (-2^-26)*den
//  * bg = !fg;  top_k tie-break via (valbits<<32)|(~idx) exact ranking;
//  * threefry partitionable split/uniform identical to jax.random.
// ============================================================================

#define THREEFRY_PARTITIONABLE 1

constexpr int kB = 16;
constexpr int kN = 12000;
constexpr int kG = 128;
constexpr int kM = kN + kG;   // 12128
constexpr int kM4 = kM / 4;   // 3032 (exact)
constexpr int kR = 256;
constexpr int kFgQuota = 64;
constexpr int kRP = 4;                    // rois per thread in k_prep
constexpr int kRoisPerBlk = 256 * kRP;    // 1024
constexpr unsigned kSeedHi = 0u;
constexpr unsigned kSeedLo = 42u;         // jax.random.key(42)

__device__ __forceinline__ int imin(int a, int b) { return a < b ? a : b; }
__device__ __forceinline__ int imax(int a, int b) { return a > b ? a : b; }

__device__ __forceinline__ unsigned rotl32(unsigned v, int d) {
  return (v << d) | (v >> (32 - d));
}

// Threefry-2x32, 20 rounds, exactly as in jax/_src/prng.py.
__device__ __forceinline__ void tf2x32(unsigned k0, unsigned k1,
                                       unsigned x0, unsigned x1,
                                       unsigned& o0, unsigned& o1) {
  const unsigned k2 = k0 ^ k1 ^ 0x1BD11BDAu;
  x0 += k0; x1 += k1;
#define TF_R(d) x0 += x1; x1 = rotl32(x1, d); x1 ^= x0;
  TF_R(13) TF_R(15) TF_R(26) TF_R(6)
  x0 += k1; x1 += k2 + 1u;
  TF_R(17) TF_R(29) TF_R(16) TF_R(24)
  x0 += k2; x1 += k0 + 2u;
  TF_R(13) TF_R(15) TF_R(26) TF_R(6)
  x0 += k0; x1 += k1 + 3u;
  TF_R(17) TF_R(29) TF_R(16) TF_R(24)
  x0 += k1; x1 += k2 + 4u;
  TF_R(13) TF_R(15) TF_R(26) TF_R(6)
  x0 += k2; x1 += k0 + 5u;
#undef TF_R
  o0 = x0; o1 = x1;
}

__device__ __forceinline__ void derive_key(int which, unsigned& ka, unsigned& kb) {
#if THREEFRY_PARTITIONABLE
  tf2x32(kSeedHi, kSeedLo, 0u, (unsigned)which, ka, kb);
#else
  unsigned a0, a1, b0, b1;
  tf2x32(kSeedHi, kSeedLo, 0u, 2u, a0, a1);
  tf2x32(kSeedHi, kSeedLo, 1u, 3u, b0, b1);
  if (which == 0) { ka = a0; kb = b0; } else { ka = a1; kb = b1; }
#endif
}

__device__ __forceinline__ float bits_to_uniform(unsigned bits) {
  return __uint_as_float((bits >> 9) | 0x3f800000u) - 1.0f;
}

__device__ __forceinline__ float jax_uniform(unsigned ka, unsigned kb, unsigned i) {
#if THREEFRY_PARTITIONABLE
  unsigned o0, o1;
  tf2x32(ka, kb, 0u, i, o0, o1);
  return bits_to_uniform(o0 ^ o1);
#else
  const unsigned H = (unsigned)(kB * kM) / 2u;
  unsigned o0, o1;
  if (i < H) { tf2x32(ka, kb, i, i + H, o0, o1); return bits_to_uniform(o0); }
  else       { tf2x32(ka, kb, i - H, i, o0, o1); return bits_to_uniform(o1); }
#endif
}

// in-mask bin: monotone in value. v in [0x40000000, 0x40400000] (2.0..3.0).
__device__ __forceinline__ unsigned mask_bin(unsigned v) {
  unsigned bn = (v - 0x40000000u) >> 11;
  return bn > 2047u ? 2047u : bn;   // exact-3.0 corner merges into top bin
}

// ---------------------------------------------------------------------------
// Kernel A: 4 rois/thread. fg mask (divide-free exact test), PRNG, vb bits.
// Grid: (ceil(kM/1024), kB) x 256.
// ---------------------------------------------------------------------------
__global__ __launch_bounds__(256) void k_prep(const float* __restrict__ all_rois,
                                              const float* __restrict__ gt_boxes,
                                              unsigned* __restrict__ vb) {
  __shared__ float4 sg[kG];
  __shared__ float sga[kG];
  const int b = blockIdx.y;
  const int tid = threadIdx.x;
  if (tid < kG) {
    const float* gp = gt_boxes + ((size_t)b * kG + tid) * 5;
    const float x0 = gp[0], y0 = gp[1], x1 = gp[2], y1 = gp[3];
    sg[tid] = make_float4(x0, y0, x1, y1);
    sga[tid] = ((x1 - x0) + 1.0f) * ((y1 - y0) + 1.0f);
  }
  __syncthreads();

  const int m0 = blockIdx.x * kRoisPerBlk + tid;
  float bx0[kRP], by0[kRP], bx1[kRP], by1[kRP], ar[kRP];
  bool valid[kRP];
#pragma unroll
  for (int k = 0; k < kRP; ++k) {
    const int m = m0 + k * 256;
    valid[k] = (m < kM);
    if (!valid[k]) {
      bx0[k] = by0[k] = bx1[k] = by1[k] = 0.0f;
    } else if (m < kN) {
      const float* rp = all_rois + ((size_t)b * kN + m) * 5;
      bx0[k] = rp[1]; by0[k] = rp[2]; bx1[k] = rp[3]; by1[k] = rp[4];
    } else {
      const float4 g4 = sg[m - kN];
      bx0[k] = g4.x; by0[k] = g4.y; bx1[k] = g4.z; by1[k] = g4.w;
    }
    ar[k] = ((bx1[k] - bx0[k]) + 1.0f) * ((by1[k] - by0[k]) + 1.0f);
  }

  bool fg[kRP] = {false, false, false, false};
#pragma unroll 2
  for (int g = 0; g < kG; ++g) {
    const float4 g4 = sg[g];
    const float ga = sga[g];
#pragma unroll
    for (int k = 0; k < kRP; ++k) {
      const float xx0 = fmaxf(bx0[k], g4.x);
      const float yy0 = fmaxf(by0[k], g4.y);
      const float xx1 = fminf(bx1[k], g4.z);
      const float yy1 = fminf(by1[k], g4.w);
      const float iw = fmaxf((xx1 - xx0) + 1.0f, 0.0f);
      const float ih = fmaxf((yy1 - yy0) + 1.0f, 0.0f);
      const float inter = iw * ih;
      const float denom = (ar[k] + ga) - inter;   // ref op order
      fg[k] = fg[k] || (__builtin_fmaf(-0.5f, denom, inter) >= (-0x1p-26f) * denom);
    }
  }

  unsigned k1a, k1b, k2a, k2b;
  derive_key(0, k1a, k1b);
  derive_key(1, k2a, k2b);
#pragma unroll
  for (int k = 0; k < kRP; ++k) {
    if (!valid[k]) continue;
    const int m = m0 + k * 256;
    const unsigned i = (unsigned)(b * kM + m);
    const float r1 = jax_uniform(k1a, k1b, i);
    const float r2 = jax_uniform(k2a, k2b, i);
    const float v1 = fg[k] ? (r1 + 2.0f) : r1;
    const float v2 = fg[k] ? r2 : (r2 + 2.0f);   // bg = !fg
    vb[(size_t)b * kM + m] = __float_as_uint(v1);
    vb[(size_t)(kB + b) * kM + m] = __float_as_uint(v2);
  }
}

__device__ __forceinline__ int block_reduce_sum(int v, int* s_red, int tid) {
#pragma unroll
  for (int off = 32; off > 0; off >>= 1) v += __shfl_down(v, off, 64);
  __syncthreads();
  if ((tid & 63) == 0) s_red[tid >> 6] = v;
  __syncthreads();
  return s_red[0] + s_red[1] + s_red[2] + s_red[3];
}

// ---------------------------------------------------------------------------
// Kernel B: one block per (which, b). Histogram in the load pass (LDS
// atomics), scan -> threshold bin -> filtered L2 re-read -> exact rank.
// ---------------------------------------------------------------------------
__global__ __launch_bounds__(256) void k_select(const unsigned* __restrict__ vb,
                                                int* __restrict__ topidx,
                                                int* __restrict__ nin) {
  __shared__ int s_hist[2048];                  // 8 KB
  __shared__ unsigned long long s_cand[1024];   // 8 KB
  __shared__ int s_scan[256];
  __shared__ int s_red[4];
  __shared__ unsigned long long s_wmax[4];
  __shared__ int s_tbin, s_cnt;

  const int which = blockIdx.x;
  const int b = blockIdx.y;
  const int tid = threadIdx.x;
  const unsigned* src = vb + (size_t)(which * kB + b) * kM;
  const uint4* src4 = (const uint4*)src;
  int* dst = topidx + (size_t)(which * kB + b) * kR;

  for (int i = tid; i < 2048; i += 256) s_hist[i] = 0;
  if (tid == 0) s_cnt = 0;
  __syncthreads();

  // pass 1: load (L2-hot) + histogram of in-mask values
  for (int i = tid; i < kM4; i += 256) {
    const uint4 u = src4[i];
#define HBIN(x) if ((x) >= 0x40000000u) atomicAdd(&s_hist[mask_bin(x)], 1);
    HBIN(u.x) HBIN(u.y) HBIN(u.z) HBIN(u.w)
#undef HBIN
  }
  __syncthreads();

  // descending 8-bin chunk per thread; n_in = sum of all bins
  const int base = 2048 - 8 * (tid + 1);
  int s = 0;
#pragma unroll
  for (int j = 0; j < 8; ++j) s += s_hist[base + j];
  const int n_in = block_reduce_sum(s, s_red, tid);
  if (tid == 0) nin[which * kB + b] = n_in;
  const int quota = (which == 0) ? kFgQuota : kR;
  const int K = imin(n_in, quota);

  if (K == 0) {
    if (which == 0) return;  // fgc==0 -> fg slots never read
    // bg degenerate: reference takes top of UNMASKED r2 -> plain argmax.
    unsigned long long best = 0ull;
    for (int m = tid; m < kM; m += 256) {
      const unsigned long long key =
          ((unsigned long long)src[m] << 32) | (unsigned)(0xFFFFFFFFu - (unsigned)m);
      if (key > best) best = key;
    }
#pragma unroll
    for (int off = 32; off > 0; off >>= 1) {
      const unsigned long long o = __shfl_down(best, off, 64);
      if (o > best) best = o;
    }
    if ((tid & 63) == 0) s_wmax[tid >> 6] = best;
    __syncthreads();
    if (tid == 0) {
      for (int w = 1; w < 4; ++w) if (s_wmax[w] > best) best = s_wmax[w];
      dst[0] = (int)(0xFFFFFFFFu - (unsigned)(best & 0xFFFFFFFFull));
    }
    return;
  }

  // inclusive scan over descending chunk sums -> threshold bin
  s_scan[tid] = s;
  __syncthreads();
  for (int off = 1; off < 256; off <<= 1) {
    const int add = (tid >= off) ? s_scan[tid - off] : 0;
    __syncthreads();
    s_scan[tid] += add;
    __syncthreads();
  }
  const int above = s_scan[tid] - s;  // count in bins above my chunk
  int cum = above;
  for (int j = 7; j >= 0; --j) {      // unique crossing bin: cum < K <= cum+c
    const int c = s_hist[base + j];
    if (cum < K && cum + c >= K) s_tbin = base + j;
    cum += c;
  }
  __syncthreads();
  const unsigned tbin = (unsigned)s_tbin;

  // pass 2: filtered re-read (L2-hot) -> candidates (~K + lambda)
  for (int i = tid; i < kM4; i += 256) {
    const uint4 u = src4[i];
#define CAND(x, j)                                                         \
    if ((x) >= 0x40000000u && mask_bin(x) >= tbin) {                       \
      const int p = atomicAdd(&s_cnt, 1);                                  \
      if (p < 1024)                                                        \
        s_cand[p] = ((unsigned long long)(x) << 32) |                      \
                    (unsigned)(0xFFFFFFFFu - (unsigned)(4 * i + (j)));     \
    }
    CAND(u.x, 0) CAND(u.y, 1) CAND(u.z, 2) CAND(u.w, 3)
#undef CAND
  }
  __syncthreads();
  const int Nc = imin(s_cnt, 1024);

  // exact rank among candidates (keys pairwise distinct)
  for (int j = tid; j < Nc; j += 256) {
    const unsigned long long key = s_cand[j];
    int rank = 0;
    for (int i = 0; i < Nc; ++i) rank += (s_cand[i] > key) ? 1 : 0;
    if (rank < K)
      dst[rank] = (int)(0xFFFFFFFFu - (unsigned)(key & 0xFFFFFFFFull));
  }
}

// ---------------------------------------------------------------------------
// Kernel C: per selected roi: reference-exact argmax over 128 gt, bbox
// transform + outputs. Grid (kB, 2) x 128 -> 32 CUs busy.
// ---------------------------------------------------------------------------
__global__ __launch_bounds__(128) void k_final(const float* __restrict__ all_rois,
                                               const float* __restrict__ gt_boxes,
                                               const int* __restrict__ topidx,
                                               const int* __restrict__ nin,
                                               float* __restrict__ out) {
  __shared__ float4 sg[kG];
  __shared__ float sga[kG];
  __shared__ float slab[kG];
  const int b = blockIdx.x;
  const int pos = blockIdx.y * 128 + threadIdx.x;
  if (threadIdx.x < kG) {   // 128 threads = full gt tile
    const float* gp = gt_boxes + ((size_t)b * kG + threadIdx.x) * 5;
    const float x0 = gp[0], y0 = gp[1], x1 = gp[2], y1 = gp[3];
    sg[threadIdx.x] = make_float4(x0, y0, x1, y1);
    sga[threadIdx.x] = ((x1 - x0) + 1.0f) * ((y1 - y0) + 1.0f);
    slab[threadIdx.x] = gp[4];
  }
  __syncthreads();

  const int fgnum = nin[b];
  const int bgnum = nin[kB + b];
  const int fgc = imin(fgnum, kFgQuota);
  const int bgav = imin(imax(bgnum, 1), kR);
  const int* fgtop = topidx + (size_t)b * kR;
  const int* bgtop = topidx + (size_t)(kB + b) * kR;

  const bool isfg = pos < fgc;
  int keep;
  if (isfg) keep = fgtop[imin(pos, imax(fgc - 1, 0))];
  else      keep = bgtop[(pos - fgc) % bgav];

  float bx0, by0, bx1, by1;
  if (keep < kN) {
    const float* rp = all_rois + ((size_t)b * kN + keep) * 5;
    bx0 = rp[1]; by0 = rp[2]; bx1 = rp[3]; by1 = rp[4];
  } else {
    const float4 g4 = sg[keep - kN];
    bx0 = g4.x; by0 = g4.y; bx1 = g4.z; by1 = g4.w;
  }
  const float areab = ((bx1 - bx0) + 1.0f) * ((by1 - by0) + 1.0f);

  // reference-exact argmax (first strict max over rounded quotients)
  float best = -1.0f;
  int a = 0;
  for (int g = 0; g < kG; ++g) {
    const float4 g4 = sg[g];
    const float xx0 = fmaxf(bx0, g4.x);
    const float yy0 = fmaxf(by0, g4.y);
    const float xx1 = fminf(bx1, g4.z);
    const float yy1 = fminf(by1, g4.w);
    const float iw = fmaxf((xx1 - xx0) + 1.0f, 0.0f);
    const float ih = fmaxf((yy1 - yy0) + 1.0f, 0.0f);
    const float inter = iw * ih;
    const float iou = inter / ((areab + sga[g]) - inter);
    if (iou > best) { best = iou; a = g; }
  }

  const float4 gt4 = sg[a];
  const float gx0 = gt4.x, gy0 = gt4.y, gx1 = gt4.z, gy1 = gt4.w;
  const float lab = isfg ? slab[a] : 0.0f;
  const float fg4 = (lab > 0.0f) ? 1.0f : 0.0f;

  const float ew = (bx1 - bx0) + 1.0f;
  const float eh = (by1 - by0) + 1.0f;
  const float ecx = bx0 + 0.5f * ew;
  const float ecy = by0 + 0.5f * eh;
  const float gw = (gx1 - gx0) + 1.0f;
  const float gh = (gy1 - gy0) + 1.0f;
  const float gcx = gx0 + 0.5f * gw;
  const float gcy = gy0 + 0.5f * gh;
  const float t0 = ((gcx - ecx) / ew) / 0.1f;
  const float t1 = ((gcy - ecy) / eh) / 0.1f;
  const float t2 = logf(gw / ew) / 0.2f;
  const float t3 = logf(gh / eh) / 0.2f;

  float* o_rois = out;                                   // [B,R,5]
  float* o_lab  = out + (size_t)kB * kR * 5;             // [B,R]
  float* o_tgt  = o_lab + (size_t)kB * kR;               // [B,R,4]
  float* o_iw   = o_tgt + (size_t)kB * kR * 4;           // [B,R,4]
  float* o_ow   = o_iw  + (size_t)kB * kR * 4;           // [B,R,4]
  const size_t p = (size_t)b * kR + pos;
  o_rois[p * 5 + 0] = (float)b;
  o_rois[p * 5 + 1] = bx0;
  o_rois[p * 5 + 2] = by0;
  o_rois[p * 5 + 3] = bx1;
  o_rois[p * 5 + 4] = by1;
  o_lab[p] = lab;
  o_tgt[p * 4 + 0] = t0 * fg4;
  o_tgt[p * 4 + 1] = t1 * fg4;
  o_tgt[p * 4 + 2] = t2 * fg4;
  o_tgt[p * 4 + 3] = t3 * fg4;
  o_iw[p * 4 + 0] = fg4; o_iw[p * 4 + 1] = fg4;
  o_iw[p * 4 + 2] = fg4; o_iw[p * 4 + 3] = fg4;
  o_ow[p * 4 + 0] = fg4; o_ow[p * 4 + 1] = fg4;
  o_ow[p * 4 + 2] = fg4; o_ow[p * 4 + 3] = fg4;
}

extern "C" void kernel_launch(void* const* d_in, const int* in_sizes, int n_in_args,
                              void* d_out, int out_size, void* d_ws, size_t ws_size,
                              hipStream_t stream) {
  (void)in_sizes; (void)n_in_args; (void)out_size; (void)ws_size;
  const float* all_rois = (const float*)d_in[0];  // [16,12000,5] fp32
  const float* gt_boxes = (const float*)d_in[1];  // [16,128,5] fp32
  float* out = (float*)d_out;

  char* ws = (char*)d_ws;
  unsigned* vb = (unsigned*)ws;                   // 2*kB*kM u32 = 1552384 B
  int* topidx  = (int*)(ws + 1572864);            // 2*kB*kR int = 32 KB
  int* nin     = (int*)(ws + 1572864 + 32768);    // 32 int

  dim3 gA((kM + kRoisPerBlk - 1) / kRoisPerBlk, kB);   // (12, 16)
  k_prep<<<gA, 256, 0, stream>>>(all_rois, gt_boxes, vb);
  dim3 gB(2, kB);
  k_select<<<gB, 256, 0, stream>>>(vb, topidx, nin);
  dim3 gC(kB, 2);
  k_final<<<gC, 128, 0, stream>>>(all_rois, gt_boxes, topidx, nin, out);
}

// Round 5
// 99.465 us; speedup vs baseline: 1.3640x; 1.3640x over previous
//
#include <hip/hip_runtime.h>
#include <cstdint>
#include <cstddef>

// ============================================================================
// ProposalTargetLayer (MSDN / Faster-RCNN), gfx950. Round 5.
// Pipeline: k_prep -> k_select -> k_final   (3 dispatches)
//  - k_prep: 1 roi/thread, 768 blocks (3 blocks/CU, 12 waves/CU TLP --
//    round-4's 192-block grid was the regression: 6.6% occupancy). Divide-
//    free exact fg test, unroll-4 g-loop (independent IoU chains), PRNG,
//    vb value-bits. No argmax here.
//  - k_select: histogram in load pass (LDS atomics) -> scan -> threshold
//    bin -> filtered L2 re-read -> exact rank (~K+6 cands). Unroll-4 loads.
//  - k_final: ONE WAVE PER OUTPUT ROI (4096 waves): lane handles 2 gt,
//    butterfly-reduce argmax on key (iou_bits<<7)|(127-g)  == reference
//    first-win argmax exactly; then transform, lane 0 stores.
// Bit-exact discrete decisions (verified rounds 1-4, absmax 0.0):
//  * fg: round(inter/denom)>=0.5 <=> fmaf(-.5,den,inter) >= (-2^-26)*den
//  * bg = !fg;  top_k tie-break via (valbits<<32)|(~idx) exact ranking;
//  * threefry partitionable split/uniform identical to jax.random;
//  * argmax: max over (iou_bits, lower-g-wins) == first strict max.
// ============================================================================

#define THREEFRY_PARTITIONABLE 1

constexpr int kB = 16;
constexpr int kN = 12000;
constexpr int kG = 128;
constexpr int kM = kN + kG;   // 12128
constexpr int kM4 = kM / 4;   // 3032 (exact)
constexpr int kR = 256;
constexpr int kFgQuota = 64;
constexpr unsigned kSeedHi = 0u;
constexpr unsigned kSeedLo = 42u;   // jax.random.key(42)

__device__ __forceinline__ int imin(int a, int b) { return a < b ? a : b; }
__device__ __forceinline__ int imax(int a, int b) { return a > b ? a : b; }

__device__ __forceinline__ unsigned rotl32(unsigned v, int d) {
  return (v << d) | (v >> (32 - d));
}

// Threefry-2x32, 20 rounds, exactly as in jax/_src/prng.py.
__device__ __forceinline__ void tf2x32(unsigned k0, unsigned k1,
                                       unsigned x0, unsigned x1,
                                       unsigned& o0, unsigned& o1) {
  const unsigned k2 = k0 ^ k1 ^ 0x1BD11BDAu;
  x0 += k0; x1 += k1;
#define TF_R(d) x0 += x1; x1 = rotl32(x1, d); x1 ^= x0;
  TF_R(13) TF_R(15) TF_R(26) TF_R(6)
  x0 += k1; x1 += k2 + 1u;
  TF_R(17) TF_R(29) TF_R(16) TF_R(24)
  x0 += k2; x1 += k0 + 2u;
  TF_R(13) TF_R(15) TF_R(26) TF_R(6)
  x0 += k0; x1 += k1 + 3u;
  TF_R(17) TF_R(29) TF_R(16) TF_R(24)
  x0 += k1; x1 += k2 + 4u;
  TF_R(13) TF_R(15) TF_R(26) TF_R(6)
  x0 += k2; x1 += k0 + 5u;
#undef TF_R
  o0 = x0; o1 = x1;
}

__device__ __forceinline__ void derive_key(int which, unsigned& ka, unsigned& kb) {
#if THREEFRY_PARTITIONABLE
  tf2x32(kSeedHi, kSeedLo, 0u, (unsigned)which, ka, kb);
#else
  unsigned a0, a1, b0, b1;
  tf2x32(kSeedHi, kSeedLo, 0u, 2u, a0, a1);
  tf2x32(kSeedHi, kSeedLo, 1u, 3u, b0, b1);
  if (which == 0) { ka = a0; kb = b0; } else { ka = a1; kb = b1; }
#endif
}

__device__ __forceinline__ float bits_to_uniform(unsigned bits) {
  return __uint_as_float((bits >> 9) | 0x3f800000u) - 1.0f;
}

__device__ __forceinline__ float jax_uniform(unsigned ka, unsigned kb, unsigned i) {
#if THREEFRY_PARTITIONABLE
  unsigned o0, o1;
  tf2x32(ka, kb, 0u, i, o0, o1);
  return bits_to_uniform(o0 ^ o1);
#else
  const unsigned H = (unsigned)(kB * kM) / 2u;
  unsigned o0, o1;
  if (i < H) { tf2x32(ka, kb, i, i + H, o0, o1); return bits_to_uniform(o0); }
  else       { tf2x32(ka, kb, i - H, i, o0, o1); return bits_to_uniform(o1); }
#endif
}

// in-mask bin: monotone in value. v in [0x40000000, 0x40400000] (2.0..3.0).
__device__ __forceinline__ unsigned mask_bin(unsigned v) {
  unsigned bn = (v - 0x40000000u) >> 11;
  return bn > 2047u ? 2047u : bn;   // exact-3.0 corner merges into top bin
}

// ---------------------------------------------------------------------------
// Kernel A: 1 roi/thread, grid (48,16)=768 blocks -> 3 blocks/CU TLP.
// fg mask (divide-free exact test), PRNG, vb value-bits.
// ---------------------------------------------------------------------------
__global__ __launch_bounds__(256) void k_prep(const float* __restrict__ all_rois,
                                              const float* __restrict__ gt_boxes,
                                              unsigned* __restrict__ vb) {
  __shared__ float4 sg[kG];
  __shared__ float sga[kG];
  const int b = blockIdx.y;
  const int tid = threadIdx.x;
  if (tid < kG) {
    const float* gp = gt_boxes + ((size_t)b * kG + tid) * 5;
    const float x0 = gp[0], y0 = gp[1], x1 = gp[2], y1 = gp[3];
    sg[tid] = make_float4(x0, y0, x1, y1);
    sga[tid] = ((x1 - x0) + 1.0f) * ((y1 - y0) + 1.0f);
  }
  __syncthreads();

  const int m = blockIdx.x * 256 + tid;
  if (m >= kM) return;

  float bx0, by0, bx1, by1;
  if (m < kN) {
    const float* rp = all_rois + ((size_t)b * kN + m) * 5;
    bx0 = rp[1]; by0 = rp[2]; bx1 = rp[3]; by1 = rp[4];
  } else {
    const float4 g4 = sg[m - kN];
    bx0 = g4.x; by0 = g4.y; bx1 = g4.z; by1 = g4.w;
  }
  const float areab = ((bx1 - bx0) + 1.0f) * ((by1 - by0) + 1.0f);

  int fg = 0;
#pragma unroll 4
  for (int g = 0; g < kG; ++g) {
    const float4 g4 = sg[g];
    const float xx0 = fmaxf(bx0, g4.x);
    const float yy0 = fmaxf(by0, g4.y);
    const float xx1 = fminf(bx1, g4.z);
    const float yy1 = fminf(by1, g4.w);
    const float iw = fmaxf((xx1 - xx0) + 1.0f, 0.0f);
    const float ih = fmaxf((yy1 - yy0) + 1.0f, 0.0f);
    const float inter = iw * ih;
    const float denom = (areab + sga[g]) - inter;   // ref op order
    fg |= (__builtin_fmaf(-0.5f, denom, inter) >= (-0x1p-26f) * denom) ? 1 : 0;
  }

  unsigned k1a, k1b, k2a, k2b;
  derive_key(0, k1a, k1b);
  derive_key(1, k2a, k2b);
  const unsigned i = (unsigned)(b * kM + m);
  const float r1 = jax_uniform(k1a, k1b, i);
  const float r2 = jax_uniform(k2a, k2b, i);
  const float v1 = fg ? (r1 + 2.0f) : r1;
  const float v2 = fg ? r2 : (r2 + 2.0f);          // bg = !fg
  vb[(size_t)b * kM + m] = __float_as_uint(v1);
  vb[(size_t)(kB + b) * kM + m] = __float_as_uint(v2);
}

__device__ __forceinline__ int block_reduce_sum(int v, int* s_red, int tid) {
#pragma unroll
  for (int off = 32; off > 0; off >>= 1) v += __shfl_down(v, off, 64);
  __syncthreads();
  if ((tid & 63) == 0) s_red[tid >> 6] = v;
  __syncthreads();
  return s_red[0] + s_red[1] + s_red[2] + s_red[3];
}

// ---------------------------------------------------------------------------
// Kernel B: one block per (which, b). Histogram in the load pass (LDS
// atomics), scan -> threshold bin -> filtered L2 re-read -> exact rank.
// ---------------------------------------------------------------------------
__global__ __launch_bounds__(256) void k_select(const unsigned* __restrict__ vb,
                                                int* __restrict__ topidx,
                                                int* __restrict__ nin) {
  __shared__ int s_hist[2048];                  // 8 KB
  __shared__ unsigned long long s_cand[1024];   // 8 KB
  __shared__ int s_scan[256];
  __shared__ int s_red[4];
  __shared__ unsigned long long s_wmax[4];
  __shared__ int s_tbin, s_cnt;

  const int which = blockIdx.x;
  const int b = blockIdx.y;
  const int tid = threadIdx.x;
  const unsigned* src = vb + (size_t)(which * kB + b) * kM;
  const uint4* src4 = (const uint4*)src;
  int* dst = topidx + (size_t)(which * kB + b) * kR;

  for (int i = tid; i < 2048; i += 256) s_hist[i] = 0;
  if (tid == 0) s_cnt = 0;
  __syncthreads();

  // pass 1: load (L2-hot) + histogram of in-mask values
#pragma unroll 4
  for (int i = tid; i < kM4; i += 256) {
    const uint4 u = src4[i];
#define HBIN(x) if ((x) >= 0x40000000u) atomicAdd(&s_hist[mask_bin(x)], 1);
    HBIN(u.x) HBIN(u.y) HBIN(u.z) HBIN(u.w)
#undef HBIN
  }
  __syncthreads();

  // descending 8-bin chunk per thread; n_in = sum of all bins
  const int base = 2048 - 8 * (tid + 1);
  int s = 0;
#pragma unroll
  for (int j = 0; j < 8; ++j) s += s_hist[base + j];
  const int n_in = block_reduce_sum(s, s_red, tid);
  if (tid == 0) nin[which * kB + b] = n_in;
  const int quota = (which == 0) ? kFgQuota : kR;
  const int K = imin(n_in, quota);

  if (K == 0) {
    if (which == 0) return;  // fgc==0 -> fg slots never read
    // bg degenerate: reference takes top of UNMASKED r2 -> plain argmax.
    unsigned long long best = 0ull;
    for (int m = tid; m < kM; m += 256) {
      const unsigned long long key =
          ((unsigned long long)src[m] << 32) | (unsigned)(0xFFFFFFFFu - (unsigned)m);
      if (key > best) best = key;
    }
#pragma unroll
    for (int off = 32; off > 0; off >>= 1) {
      const unsigned long long o = __shfl_down(best, off, 64);
      if (o > best) best = o;
    }
    if ((tid & 63) == 0) s_wmax[tid >> 6] = best;
    __syncthreads();
    if (tid == 0) {
      for (int w = 1; w < 4; ++w) if (s_wmax[w] > best) best = s_wmax[w];
      dst[0] = (int)(0xFFFFFFFFu - (unsigned)(best & 0xFFFFFFFFull));
    }
    return;
  }

  // inclusive scan over descending chunk sums -> threshold bin
  s_scan[tid] = s;
  __syncthreads();
  for (int off = 1; off < 256; off <<= 1) {
    const int add = (tid >= off) ? s_scan[tid - off] : 0;
    __syncthreads();
    s_scan[tid] += add;
    __syncthreads();
  }
  const int above = s_scan[tid] - s;  // count in bins above my chunk
  int cum = above;
  for (int j = 7; j >= 0; --j) {      // unique crossing bin: cum < K <= cum+c
    const int c = s_hist[base + j];
    if (cum < K && cum + c >= K) s_tbin = base + j;
    cum += c;
  }
  __syncthreads();
  const unsigned tbin = (unsigned)s_tbin;

  // pass 2: filtered re-read (L2-hot) -> candidates (~K + lambda)
#pragma unroll 4
  for (int i = tid; i < kM4; i += 256) {
    const uint4 u = src4[i];
#define CAND(x, j)                                                         \
    if ((x) >= 0x40000000u && mask_bin(x) >= tbin) {                       \
      const int p = atomicAdd(&s_cnt, 1);                                  \
      if (p < 1024)                                                        \
        s_cand[p] = ((unsigned long long)(x) << 32) |                      \
                    (unsigned)(0xFFFFFFFFu - (unsigned)(4 * i + (j)));     \
    }
    CAND(u.x, 0) CAND(u.y, 1) CAND(u.z, 2) CAND(u.w, 3)
#undef CAND
  }
  __syncthreads();
  const int Nc = imin(s_cnt, 1024);

  // exact rank among candidates (keys pairwise distinct)
  for (int j = tid; j < Nc; j += 256) {
    const unsigned long long key = s_cand[j];
    int rank = 0;
    for (int i = 0; i < Nc; ++i) rank += (s_cand[i] > key) ? 1 : 0;
    if (rank < K)
      dst[rank] = (int)(0xFFFFFFFFu - (unsigned)(key & 0xFFFFFFFFull));
  }
}

// ---------------------------------------------------------------------------
// Kernel C: one WAVE per output roi (4096 waves, 1024 blocks x 256).
// Lane l handles gt {l, l+64}; butterfly argmax on (iou_bits<<7)|(127-g)
// == reference first-win argmax. Lane 0 writes the 18 outputs.
// ---------------------------------------------------------------------------
__global__ __launch_bounds__(256) void k_final(const float* __restrict__ all_rois,
                                               const float* __restrict__ gt_boxes,
                                               const int* __restrict__ topidx,
                                               const int* __restrict__ nin,
                                               float* __restrict__ out) {
  const int lane = threadIdx.x & 63;
  const int idx = (blockIdx.x << 2) | (threadIdx.x >> 6);  // roi id 0..4095
  const int b = idx >> 8;
  const int pos = idx & 255;

  const int fgc = imin(nin[b], kFgQuota);
  const int bgav = imin(imax(nin[kB + b], 1), kR);
  const bool isfg = pos < fgc;
  int keep;
  if (isfg) keep = topidx[(size_t)b * kR + imin(pos, imax(fgc - 1, 0))];
  else      keep = topidx[(size_t)(kB + b) * kR + (pos - fgc) % bgav];

  const float* bp = (keep < kN) ? (all_rois + ((size_t)b * kN + keep) * 5 + 1)
                                : (gt_boxes + ((size_t)b * kG + (keep - kN)) * 5);
  const float bx0 = bp[0], by0 = bp[1], bx1 = bp[2], by1 = bp[3];
  const float areab = ((bx1 - bx0) + 1.0f) * ((by1 - by0) + 1.0f);

  unsigned long long best = 0ull;
#pragma unroll
  for (int h = 0; h < 2; ++h) {
    const int g = lane + 64 * h;
    const float* gp = gt_boxes + ((size_t)b * kG + g) * 5;
    const float gx0 = gp[0], gy0 = gp[1], gx1 = gp[2], gy1 = gp[3];
    const float ga = ((gx1 - gx0) + 1.0f) * ((gy1 - gy0) + 1.0f);
    const float xx0 = fmaxf(bx0, gx0);
    const float yy0 = fmaxf(by0, gy0);
    const float xx1 = fminf(bx1, gx1);
    const float yy1 = fminf(by1, gy1);
    const float iw = fmaxf((xx1 - xx0) + 1.0f, 0.0f);
    const float ih = fmaxf((yy1 - yy0) + 1.0f, 0.0f);
    const float inter = iw * ih;
    const float iou = inter / ((areab + ga) - inter);   // ref-exact f32 div
    const unsigned long long key =
        ((unsigned long long)__float_as_uint(iou) << 7) | (unsigned)(127 - g);
    if (key > best) best = key;
  }
#pragma unroll
  for (int off = 1; off < 64; off <<= 1) {
    const unsigned long long o = __shfl_xor(best, off, 64);
    if (o > best) best = o;
  }
  const int a = 127 - (int)(best & 127ull);

  const float* gp = gt_boxes + ((size_t)b * kG + a) * 5;
  const float gx0 = gp[0], gy0 = gp[1], gx1 = gp[2], gy1 = gp[3];
  const float lab = isfg ? gp[4] : 0.0f;
  const float fg4 = (lab > 0.0f) ? 1.0f : 0.0f;

  const float ew = (bx1 - bx0) + 1.0f;
  const float eh = (by1 - by0) + 1.0f;
  const float ecx = bx0 + 0.5f * ew;
  const float ecy = by0 + 0.5f * eh;
  const float gw = (gx1 - gx0) + 1.0f;
  const float gh = (gy1 - gy0) + 1.0f;
  const float gcx = gx0 + 0.5f * gw;
  const float gcy = gy0 + 0.5f * gh;
  const float t0 = ((gcx - ecx) / ew) / 0.1f;
  const float t1 = ((gcy - ecy) / eh) / 0.1f;
  const float t2 = logf(gw / ew) / 0.2f;
  const float t3 = logf(gh / eh) / 0.2f;

  if (lane == 0) {
    float* o_rois = out;                                   // [B,R,5]
    float* o_lab  = out + (size_t)kB * kR * 5;             // [B,R]
    float* o_tgt  = o_lab + (size_t)kB * kR;               // [B,R,4]
    float* o_iw   = o_tgt + (size_t)kB * kR * 4;           // [B,R,4]
    float* o_ow   = o_iw  + (size_t)kB * kR * 4;           // [B,R,4]
    const size_t p = (size_t)b * kR + pos;
    o_rois[p * 5 + 0] = (float)b;
    o_rois[p * 5 + 1] = bx0;
    o_rois[p * 5 + 2] = by0;
    o_rois[p * 5 + 3] = bx1;
    o_rois[p * 5 + 4] = by1;
    o_lab[p] = lab;
    o_tgt[p * 4 + 0] = t0 * fg4;
    o_tgt[p * 4 + 1] = t1 * fg4;
    o_tgt[p * 4 + 2] = t2 * fg4;
    o_tgt[p * 4 + 3] = t3 * fg4;
    o_iw[p * 4 + 0] = fg4; o_iw[p * 4 + 1] = fg4;
    o_iw[p * 4 + 2] = fg4; o_iw[p * 4 + 3] = fg4;
    o_ow[p * 4 + 0] = fg4; o_ow[p * 4 + 1] = fg4;
    o_ow[p * 4 + 2] = fg4; o_ow[p * 4 + 3] = fg4;
  }
}

extern "C" void kernel_launch(void* const* d_in, const int* in_sizes, int n_in_args,
                              void* d_out, int out_size, void* d_ws, size_t ws_size,
                              hipStream_t stream) {
  (void)in_sizes; (void)n_in_args; (void)out_size; (void)ws_size;
  const float* all_rois = (const float*)d_in[0];  // [16,12000,5] fp32
  const float* gt_boxes = (const float*)d_in[1];  // [16,128,5] fp32
  float* out = (float*)d_out;

  char* ws = (char*)d_ws;
  unsigned* vb = (unsigned*)ws;                   // 2*kB*kM u32 = 1552384 B
  int* topidx  = (int*)(ws + 1572864);            // 2*kB*kR int = 32 KB
  int* nin     = (int*)(ws + 1572864 + 32768);    // 32 int

  dim3 gA((kM + 255) / 256, kB);                  // (48, 16) = 768 blocks
  k_prep<<<gA, 256, 0, stream>>>(all_rois, gt_boxes, vb);
  dim3 gB(2, kB);
  k_select<<<gB, 256, 0, stream>>>(vb, topidx, nin);
  k_final<<<1024, 256, 0, stream>>>(all_rois, gt_boxes, topidx, nin, out);
}

// Round 7
// 87.497 us; speedup vs baseline: 1.5506x; 1.1368x over previous
//
#include <hip/hip_runtime.h>
#include <cstdint>
#include <cstddef>

// ============================================================================
// ProposalTargetLayer (MSDN / Faster-RCNN), gfx950. Round 7.
// Round 6 with the one-line channel-boost fix in k_prep:
//   v = (fg ^ h) ? (r + 2.0f) : r      (+2.0 iff fg^h==1)
// h=0 (r1/fg channel): +2 iff fg.  h=1 (r2/bg channel): +2 iff !fg.
// Round 6 had the ternary arms swapped -> fg/bg masks exchanged -> absmax 724.
//
// Pipeline: k_prep -> k_select -> k_final   (3 dispatches)
//  - k_prep: TWO threads per roi (gt-half split h=0/1). Each thread: 64 IoU
//    tests (divide-free exact fg test) + ONE threefry hash (its channel);
//    partial fg merged via LDS; h writes vb row (h*kB+b). 1520 blocks ->
//    ~6 waves/SIMD.
//  - k_select: 1024 threads/block: pass1 hist-on-load, scan -> threshold
//    bin, pass2 filtered candidates, exact rank. 32 blocks.
//  - k_final: one wave per output roi; butterfly argmax on
//    (iou_bits<<7)|(127-g) == reference first-win argmax.
// Bit-exact discrete decisions (verified rounds 1-5, absmax 0.0):
//  * fg: round(inter/denom)>=0.5 <=> fmaf(-.5,den,inter) >= (-2^-26)*den
//  * bg = !fg;  top_k tie-break via (valbits<<32)|(~idx) exact ranking;
//  * threefry partitionable split/uniform identical to jax.random;
//  * argmax: max over (iou_bits, lower-g-wins) == first strict max.
// ============================================================================

#define THREEFRY_PARTITIONABLE 1

constexpr int kB = 16;
constexpr int kN = 12000;
constexpr int kG = 128;
constexpr int kM = kN + kG;   // 12128
constexpr int kM4 = kM / 4;   // 3032 (exact)
constexpr int kR = 256;
constexpr int kFgQuota = 64;
constexpr unsigned kSeedHi = 0u;
constexpr unsigned kSeedLo = 42u;   // jax.random.key(42)

__device__ __forceinline__ int imin(int a, int b) { return a < b ? a : b; }
__device__ __forceinline__ int imax(int a, int b) { return a > b ? a : b; }

__device__ __forceinline__ unsigned rotl32(unsigned v, int d) {
  return (v << d) | (v >> (32 - d));
}

// Threefry-2x32, 20 rounds, exactly as in jax/_src/prng.py.
__device__ __forceinline__ void tf2x32(unsigned k0, unsigned k1,
                                       unsigned x0, unsigned x1,
                                       unsigned& o0, unsigned& o1) {
  const unsigned k2 = k0 ^ k1 ^ 0x1BD11BDAu;
  x0 += k0; x1 += k1;
#define TF_R(d) x0 += x1; x1 = rotl32(x1, d); x1 ^= x0;
  TF_R(13) TF_R(15) TF_R(26) TF_R(6)
  x0 += k1; x1 += k2 + 1u;
  TF_R(17) TF_R(29) TF_R(16) TF_R(24)
  x0 += k2; x1 += k0 + 2u;
  TF_R(13) TF_R(15) TF_R(26) TF_R(6)
  x0 += k0; x1 += k1 + 3u;
  TF_R(17) TF_R(29) TF_R(16) TF_R(24)
  x0 += k1; x1 += k2 + 4u;
  TF_R(13) TF_R(15) TF_R(26) TF_R(6)
  x0 += k2; x1 += k0 + 5u;
#undef TF_R
  o0 = x0; o1 = x1;
}

// Both keys const-folded (literal inputs), then select by (wave-uniform) h.
__device__ __forceinline__ void derive_key(int which, unsigned& ka, unsigned& kb) {
#if THREEFRY_PARTITIONABLE
  unsigned a0, a1, b0, b1;
  tf2x32(kSeedHi, kSeedLo, 0u, 0u, a0, a1);
  tf2x32(kSeedHi, kSeedLo, 0u, 1u, b0, b1);
  ka = which ? b0 : a0;
  kb = which ? b1 : a1;
#else
  unsigned a0, a1, b0, b1;
  tf2x32(kSeedHi, kSeedLo, 0u, 2u, a0, a1);
  tf2x32(kSeedHi, kSeedLo, 1u, 3u, b0, b1);
  ka = which ? a1 : a0;
  kb = which ? b1 : b0;
#endif
}

__device__ __forceinline__ float bits_to_uniform(unsigned bits) {
  return __uint_as_float((bits >> 9) | 0x3f800000u) - 1.0f;
}

__device__ __forceinline__ float jax_uniform(unsigned ka, unsigned kb, unsigned i) {
#if THREEFRY_PARTITIONABLE
  unsigned o0, o1;
  tf2x32(ka, kb, 0u, i, o0, o1);
  return bits_to_uniform(o0 ^ o1);
#else
  const unsigned H = (unsigned)(kB * kM) / 2u;
  unsigned o0, o1;
  if (i < H) { tf2x32(ka, kb, i, i + H, o0, o1); return bits_to_uniform(o0); }
  else       { tf2x32(ka, kb, i - H, i, o0, o1); return bits_to_uniform(o1); }
#endif
}

// in-mask bin: monotone in value. v in [0x40000000, 0x40400000] (2.0..3.0).
__device__ __forceinline__ unsigned mask_bin(unsigned v) {
  unsigned bn = (v - 0x40000000u) >> 11;
  return bn > 2047u ? 2047u : bn;   // exact-3.0 corner merges into top bin
}

// ---------------------------------------------------------------------------
// Kernel A: 2 threads per roi (gt-half split). Block 256 thr = 128 rois x 2.
// Grid ((kM+127)/128, kB) = (95,16) = 1520 blocks -> ~6 waves/SIMD.
// ---------------------------------------------------------------------------
__global__ __launch_bounds__(256) void k_prep(const float* __restrict__ all_rois,
                                              const float* __restrict__ gt_boxes,
                                              unsigned* __restrict__ vb) {
  __shared__ float4 sg[kG];
  __shared__ float sga[kG];
  __shared__ int s_fgp[2][128];
  const int b = blockIdx.y;
  const int tid = threadIdx.x;
  if (tid < kG) {
    const float* gp = gt_boxes + ((size_t)b * kG + tid) * 5;
    const float x0 = gp[0], y0 = gp[1], x1 = gp[2], y1 = gp[3];
    sg[tid] = make_float4(x0, y0, x1, y1);
    sga[tid] = ((x1 - x0) + 1.0f) * ((y1 - y0) + 1.0f);
  }
  const int rl = tid & 127;          // roi within block
  const int h = tid >> 7;            // gt half 0/1 (wave-uniform)
  const int m = blockIdx.x * 128 + rl;
  const bool valid = (m < kM);
  __syncthreads();

  float bx0 = 0.f, by0 = 0.f, bx1 = 0.f, by1 = 0.f;
  if (valid) {
    if (m < kN) {
      const float* rp = all_rois + ((size_t)b * kN + m) * 5;
      bx0 = rp[1]; by0 = rp[2]; bx1 = rp[3]; by1 = rp[4];
    } else {
      const float4 g4 = sg[m - kN];
      bx0 = g4.x; by0 = g4.y; bx1 = g4.z; by1 = g4.w;
    }
  }
  const float areab = ((bx1 - bx0) + 1.0f) * ((by1 - by0) + 1.0f);

  int fgp = 0;
  const int g0 = h * 64;
#pragma unroll 8
  for (int gg = 0; gg < 64; ++gg) {
    const int g = g0 + gg;
    const float4 g4 = sg[g];
    const float xx0 = fmaxf(bx0, g4.x);
    const float yy0 = fmaxf(by0, g4.y);
    const float xx1 = fminf(bx1, g4.z);
    const float yy1 = fminf(by1, g4.w);
    const float iw = fmaxf((xx1 - xx0) + 1.0f, 0.0f);
    const float ih = fmaxf((yy1 - yy0) + 1.0f, 0.0f);
    const float inter = iw * ih;
    const float denom = (areab + sga[g]) - inter;   // ref op order
    fgp |= (__builtin_fmaf(-0.5f, denom, inter) >= (-0x1p-26f) * denom) ? 1 : 0;
  }
  s_fgp[h][rl] = fgp;
  __syncthreads();
  if (!valid) return;
  const int fg = s_fgp[0][rl] | s_fgp[1][rl];   // exists-g over both halves

  unsigned ka, kb;
  derive_key(h, ka, kb);                        // h wave-uniform select
  const unsigned i = (unsigned)(b * kM + m);
  const float r = jax_uniform(ka, kb, i);
  // h=0: fg channel (r1): +2 iff fg.  h=1: bg channel (r2): +2 iff !fg.
  // => +2.0 exactly when (fg ^ h) == 1.   (Round 6 had the arms swapped.)
  const float v = (fg ^ h) ? (r + 2.0f) : r;
  vb[(size_t)(h * kB + b) * kM + m] = __float_as_uint(v);
}

// block reduce over nw waves (nw <= 16)
__device__ __forceinline__ int block_reduce_sum_w(int v, int* s_red, int tid, int nw) {
#pragma unroll
  for (int off = 32; off > 0; off >>= 1) v += __shfl_down(v, off, 64);
  __syncthreads();
  if ((tid & 63) == 0) s_red[tid >> 6] = v;
  __syncthreads();
  int t = 0;
  for (int w = 0; w < nw; ++w) t += s_red[w];
  return t;
}

// ---------------------------------------------------------------------------
// Kernel B: one block per (which, b), 1024 threads.
// Histogram on load, scan (first 256 threads) -> threshold bin, filtered
// re-read -> exact rank of ~K+6 candidates.
// ---------------------------------------------------------------------------
__global__ __launch_bounds__(1024) void k_select(const unsigned* __restrict__ vb,
                                                 int* __restrict__ topidx,
                                                 int* __restrict__ nin) {
  __shared__ int s_hist[2048];                  // 8 KB
  __shared__ unsigned long long s_cand[1024];   // 8 KB
  __shared__ int s_scan[256];
  __shared__ int s_red[16];
  __shared__ unsigned long long s_wmax[16];
  __shared__ int s_tbin, s_cnt;

  const int which = blockIdx.x;
  const int b = blockIdx.y;
  const int tid = threadIdx.x;
  const unsigned* src = vb + (size_t)(which * kB + b) * kM;
  const uint4* src4 = (const uint4*)src;
  int* dst = topidx + (size_t)(which * kB + b) * kR;

  for (int i = tid; i < 2048; i += 1024) s_hist[i] = 0;
  if (tid == 0) s_cnt = 0;
  __syncthreads();

  // pass 1: load (L2-hot) + histogram of in-mask values (3 uint4/thread)
  for (int i = tid; i < kM4; i += 1024) {
    const uint4 u = src4[i];
#define HBIN(x) if ((x) >= 0x40000000u) atomicAdd(&s_hist[mask_bin(x)], 1);
    HBIN(u.x) HBIN(u.y) HBIN(u.z) HBIN(u.w)
#undef HBIN
  }
  __syncthreads();

  // chunk sums: first 256 threads own descending 8-bin chunks
  int s = 0;
  if (tid < 256) {
    const int base = 2048 - 8 * (tid + 1);
#pragma unroll
    for (int j = 0; j < 8; ++j) s += s_hist[base + j];
    s_scan[tid] = s;
  }
  const int n_in = block_reduce_sum_w((tid < 256) ? s : 0, s_red, tid, 16);
  if (tid == 0) nin[which * kB + b] = n_in;
  const int quota = (which == 0) ? kFgQuota : kR;
  const int K = imin(n_in, quota);

  if (K == 0) {
    if (which == 0) return;  // fgc==0 -> fg slots never read
    // bg degenerate: reference takes top of UNMASKED r2 -> plain argmax.
    unsigned long long best = 0ull;
    for (int m = tid; m < kM; m += 1024) {
      const unsigned long long key =
          ((unsigned long long)src[m] << 32) | (unsigned)(0xFFFFFFFFu - (unsigned)m);
      if (key > best) best = key;
    }
#pragma unroll
    for (int off = 32; off > 0; off >>= 1) {
      const unsigned long long o = __shfl_down(best, off, 64);
      if (o > best) best = o;
    }
    __syncthreads();
    if ((tid & 63) == 0) s_wmax[tid >> 6] = best;
    __syncthreads();
    if (tid == 0) {
      for (int w = 1; w < 16; ++w) if (s_wmax[w] > best) best = s_wmax[w];
      dst[0] = (int)(0xFFFFFFFFu - (unsigned)(best & 0xFFFFFFFFull));
    }
    return;
  }

  // inclusive scan over the 256 descending chunk sums -> threshold bin
  __syncthreads();
  for (int off = 1; off < 256; off <<= 1) {
    int add = 0;
    if (tid < 256 && tid >= off) add = s_scan[tid - off];
    __syncthreads();
    if (tid < 256) s_scan[tid] += add;
    __syncthreads();
  }
  if (tid < 256) {
    const int base = 2048 - 8 * (tid + 1);
    int s2 = 0;
#pragma unroll
    for (int j = 0; j < 8; ++j) s2 += s_hist[base + j];
    const int above = s_scan[tid] - s2;  // count in bins above my chunk
    int cum = above;
    for (int j = 7; j >= 0; --j) {       // unique crossing: cum < K <= cum+c
      const int c = s_hist[base + j];
      if (cum < K && cum + c >= K) s_tbin = base + j;
      cum += c;
    }
  }
  __syncthreads();
  const unsigned tbin = (unsigned)s_tbin;

  // pass 2: filtered re-read (L2-hot) -> candidates (~K + lambda)
  for (int i = tid; i < kM4; i += 1024) {
    const uint4 u = src4[i];
#define CAND(x, j)                                                         \
    if ((x) >= 0x40000000u && mask_bin(x) >= tbin) {                       \
      const int p = atomicAdd(&s_cnt, 1);                                  \
      if (p < 1024)                                                        \
        s_cand[p] = ((unsigned long long)(x) << 32) |                      \
                    (unsigned)(0xFFFFFFFFu - (unsigned)(4 * i + (j)));     \
    }
    CAND(u.x, 0) CAND(u.y, 1) CAND(u.z, 2) CAND(u.w, 3)
#undef CAND
  }
  __syncthreads();
  const int Nc = imin(s_cnt, 1024);

  // exact rank among candidates (keys pairwise distinct)
  for (int j = tid; j < Nc; j += 1024) {
    const unsigned long long key = s_cand[j];
    int rank = 0;
    for (int i = 0; i < Nc; ++i) rank += (s_cand[i] > key) ? 1 : 0;
    if (rank < K)
      dst[rank] = (int)(0xFFFFFFFFu - (unsigned)(key & 0xFFFFFFFFull));
  }
}

// ---------------------------------------------------------------------------
// Kernel C: one WAVE per output roi (4096 waves, 1024 blocks x 256).
// Lane l handles gt {l, l+64}; butterfly argmax on (iou_bits<<7)|(127-g)
// == reference first-win argmax. Lane 0 writes the 18 outputs.
// ---------------------------------------------------------------------------
__global__ __launch_bounds__(256) void k_final(const float* __restrict__ all_rois,
                                               const float* __restrict__ gt_boxes,
                                               const int* __restrict__ topidx,
                                               const int* __restrict__ nin,
                                               float* __restrict__ out) {
  const int lane = threadIdx.x & 63;
  const int idx = (blockIdx.x << 2) | (threadIdx.x >> 6);  // roi id 0..4095
  const int b = idx >> 8;
  const int pos = idx & 255;

  const int fgc = imin(nin[b], kFgQuota);
  const int bgav = imin(imax(nin[kB + b], 1), kR);
  const bool isfg = pos < fgc;
  int keep;
  if (isfg) keep = topidx[(size_t)b * kR + imin(pos, imax(fgc - 1, 0))];
  else      keep = topidx[(size_t)(kB + b) * kR + (pos - fgc) % bgav];

  const float* bp = (keep < kN) ? (all_rois + ((size_t)b * kN + keep) * 5 + 1)
                                : (gt_boxes + ((size_t)b * kG + (keep - kN)) * 5);
  const float bx0 = bp[0], by0 = bp[1], bx1 = bp[2], by1 = bp[3];
  const float areab = ((bx1 - bx0) + 1.0f) * ((by1 - by0) + 1.0f);

  unsigned long long best = 0ull;
#pragma unroll
  for (int h = 0; h < 2; ++h) {
    const int g = lane + 64 * h;
    const float* gp = gt_boxes + ((size_t)b * kG + g) * 5;
    const float gx0 = gp[0], gy0 = gp[1], gx1 = gp[2], gy1 = gp[3];
    const float ga = ((gx1 - gx0) + 1.0f) * ((gy1 - gy0) + 1.0f);
    const float xx0 = fmaxf(bx0, gx0);
    const float yy0 = fmaxf(by0, gy0);
    const float xx1 = fminf(bx1, gx1);
    const float yy1 = fminf(by1, gy1);
    const float iw = fmaxf((xx1 - xx0) + 1.0f, 0.0f);
    const float ih = fmaxf((yy1 - yy0) + 1.0f, 0.0f);
    const float inter = iw * ih;
    const float iou = inter / ((areab + ga) - inter);   // ref-exact f32 div
    const unsigned long long key =
        ((unsigned long long)__float_as_uint(iou) << 7) | (unsigned)(127 - g);
    if (key > best) best = key;
  }
#pragma unroll
  for (int off = 1; off < 64; off <<= 1) {
    const unsigned long long o = __shfl_xor(best, off, 64);
    if (o > best) best = o;
  }
  const int a = 127 - (int)(best & 127ull);

  const float* gp = gt_boxes + ((size_t)b * kG + a) * 5;
  const float gx0 = gp[0], gy0 = gp[1], gx1 = gp[2], gy1 = gp[3];
  const float lab = isfg ? gp[4] : 0.0f;
  const float fg4 = (lab > 0.0f) ? 1.0f : 0.0f;

  const float ew = (bx1 - bx0) + 1.0f;
  const float eh = (by1 - by0) + 1.0f;
  const float ecx = bx0 + 0.5f * ew;
  const float ecy = by0 + 0.5f * eh;
  const float gw = (gx1 - gx0) + 1.0f;
  const float gh = (gy1 - gy0) + 1.0f;
  const float gcx = gx0 + 0.5f * gw;
  const float gcy = gy0 + 0.5f * gh;
  const float t0 = ((gcx - ecx) / ew) / 0.1f;
  const float t1 = ((gcy - ecy) / eh) / 0.1f;
  const float t2 = logf(gw / ew) / 0.2f;
  const float t3 = logf(gh / eh) / 0.2f;

  if (lane == 0) {
    float* o_rois = out;                                   // [B,R,5]
    float* o_lab  = out + (size_t)kB * kR * 5;             // [B,R]
    float* o_tgt  = o_lab + (size_t)kB * kR;               // [B,R,4]
    float* o_iw   = o_tgt + (size_t)kB * kR * 4;           // [B,R,4]
    float* o_ow   = o_iw  + (size_t)kB * kR * 4;           // [B,R,4]
    const size_t p = (size_t)b * kR + pos;
    o_rois[p * 5 + 0] = (float)b;
    o_rois[p * 5 + 1] = bx0;
    o_rois[p * 5 + 2] = by0;
    o_rois[p * 5 + 3] = bx1;
    o_rois[p * 5 + 4] = by1;
    o_lab[p] = lab;
    o_tgt[p * 4 + 0] = t0 * fg4;
    o_tgt[p * 4 + 1] = t1 * fg4;
    o_tgt[p * 4 + 2] = t2 * fg4;
    o_tgt[p * 4 + 3] = t3 * fg4;
    o_iw[p * 4 + 0] = fg4; o_iw[p * 4 + 1] = fg4;
    o_iw[p * 4 + 2] = fg4; o_iw[p * 4 + 3] = fg4;
    o_ow[p * 4 + 0] = fg4; o_ow[p * 4 + 1] = fg4;
    o_ow[p * 4 + 2] = fg4; o_ow[p * 4 + 3] = fg4;
  }
}

extern "C" void kernel_launch(void* const* d_in, const int* in_sizes, int n_in_args,
                              void* d_out, int out_size, void* d_ws, size_t ws_size,
                              hipStream_t stream) {
  (void)in_sizes; (void)n_in_args; (void)out_size; (void)ws_size;
  const float* all_rois = (const float*)d_in[0];  // [16,12000,5] fp32
  const float* gt_boxes = (const float*)d_in[1];  // [16,128,5] fp32
  float* out = (float*)d_out;

  char* ws = (char*)d_ws;
  unsigned* vb = (unsigned*)ws;                   // 2*kB*kM u32 = 1552384 B
  int* topidx  = (int*)(ws + 1572864);            // 2*kB*kR int = 32 KB
  int* nin     = (int*)(ws + 1572864 + 32768);    // 32 int

  dim3 gA((kM + 127) / 128, kB);                  // (95, 16) = 1520 blocks
  k_prep<<<gA, 256, 0, stream>>>(all_rois, gt_boxes, vb);
  dim3 gB(2, kB);
  k_select<<<gB, 1024, 0, stream>>>(vb, topidx, nin);
  k_final<<<1024, 256, 0, stream>>>(all_rois, gt_boxes, topidx, nin, out);
}